// Round 6
// baseline (129.842 us; speedup 1.0000x reference)
//
#include <hip/hip_runtime.h>

typedef _Float16 h2 __attribute__((ext_vector_type(2)));
typedef unsigned short u2 __attribute__((ext_vector_type(2)));

static constexpr int N_AGENTS = 64;   // = wave size; one lane per agent/edge
static constexpr int H_DIM    = 8;
static constexpr int ROWS     = 4;    // rows per wave-iteration = 2 f16x2 pairs

__device__ __forceinline__ h2 h2splat(float v) {
    _Float16 h = (_Float16)v;
    return (h2){h, h};
}

__device__ __forceinline__ h2 pack2(float a, float b) {
#if __has_builtin(__builtin_amdgcn_cvt_pkrtz)
    auto r = __builtin_amdgcn_cvt_pkrtz(a, b);   // v_cvt_pkrtz_f16_f32 (1 instr)
    h2 out; __builtin_memcpy(&out, &r, 4); return out;
#else
    return (h2){(_Float16)a, (_Float16)b};
#endif
}

// Packed-f16 tanh via Pade[5/4]: tanh(t) ~= t*(945+105u+u^2)/(945+420u+15u^2),
// u=t^2, num/den normalized by 945 so Q in [1, 8.9]. Input clamped to +-3.5
// (poly err <= 1.1e-3 incl. saturation; f16-safe ranges). Division replaced by
// packed u16 bit-hack reciprocal (r0 = bitcast(0x7789 - bits(Q)), ~6% err)
// + 2 packed Newton steps -> rel err ~1e-5. ZERO transcendentals, all VOP3P.
struct TanhConsts {
    h2 c3p5, mc3p5, c1p, c2p, c1q, c2q, one, two;
    u2 K;
};

__device__ __forceinline__ h2 tanh_pk(h2 t, const TanhConsts& C) {
    t = __builtin_elementwise_min(t, C.c3p5);
    t = __builtin_elementwise_max(t, C.mc3p5);
    const h2 u = t * t;                                  // v_pk_mul_f16
    h2 P = __builtin_elementwise_fma(u, C.c2p, C.c1p);
    P = __builtin_elementwise_fma(u, P, C.one);
    h2 Q = __builtin_elementwise_fma(u, C.c2q, C.c1q);
    Q = __builtin_elementwise_fma(u, Q, C.one);
    u2 qb; __builtin_memcpy(&qb, &Q, 4);
    u2 rb = C.K - qb;                                    // v_pk_sub_u16
    h2 r;  __builtin_memcpy(&r, &rb, 4);
    h2 m = __builtin_elementwise_fma(-Q, r, C.two);      // 2 - Q*r
    r = r * m;
    m = __builtin_elementwise_fma(-Q, r, C.two);
    r = r * m;
    return (t * P) * r;
}

__global__ __launch_bounds__(256) void networked_ode_kernel(
    const float* __restrict__ x,    // [B, N] f32
    const float* __restrict__ W1,   // [N, H]
    const float* __restrict__ b1,   // [N, H]
    const float* __restrict__ W2,   // [N, H]
    const float* __restrict__ b2,   // [N]
    const float* __restrict__ Wc1,  // [2, H]
    const float* __restrict__ bc1,  // [H]
    const float* __restrict__ Wc2,  // [H]
    const float* __restrict__ bc2,  // [1]
    const int* __restrict__ send_idx,  // [N]
    const int* __restrict__ recv_idx,  // [N]
    float* __restrict__ out,        // [B, N] f32
    int B)
{
    const int lane           = threadIdx.x & 63;
    const int wave_in_block  = threadIdx.x >> 6;
    const int waves_per_blk  = blockDim.x >> 6;
    const int gwave          = blockIdx.x * waves_per_blk + wave_in_block;
    const int total_waves    = gridDim.x * waves_per_blk;

    TanhConsts TC;
    TC.c3p5  = h2splat(3.5f);
    TC.mc3p5 = h2splat(-3.5f);
    TC.c1p   = h2splat(105.0f / 945.0f);
    TC.c2p   = h2splat(1.0f / 945.0f);
    TC.c1q   = h2splat(420.0f / 945.0f);
    TC.c2q   = h2splat(15.0f / 945.0f);
    TC.one   = h2splat(1.0f);
    TC.two   = h2splat(2.0f);
    TC.K     = (u2){0x7789, 0x7789};

    // ---- per-lane (agent) intrinsic weights: layer-1 f32, layer-2 packed f16
    float w1v[H_DIM], b1v[H_DIM];
    h2 w2h[H_DIM];
#pragma unroll
    for (int h = 0; h < H_DIM; ++h) {
        w1v[h] = W1[lane * H_DIM + h];
        b1v[h] = b1[lane * H_DIM + h];
        w2h[h] = h2splat(W2[lane * H_DIM + h]);
    }
    const h2 a0h = h2splat(b2[lane]);

    // ---- wave-uniform coupling weights
    float wcs[H_DIM], wcr[H_DIM], bc1v[H_DIM];
    h2 wc2h[H_DIM];
#pragma unroll
    for (int h = 0; h < H_DIM; ++h) {
        wcs[h]  = Wc1[h];          // Wc1[0][h] (x_send)
        wcr[h]  = Wc1[H_DIM + h];  // Wc1[1][h] (x_recv)
        bc1v[h] = bc1[h];
        wc2h[h] = h2splat(Wc2[h]);
    }
    const h2 c0h = h2splat(bc2[0]);

    // ---- edge endpoints for edge e = lane
    const int sidx = send_idx[lane];
    const int ridx = recv_idx[lane];

    // ring topology: send is identity in practice; detect wave-uniformly
    const bool send_is_id = (__ballot(sidx == lane) == ~0ull);

    // ---- scatter-add becomes gather via inverse permutation (computed once)
    __shared__ int inv_r_s[256], inv_s_s[256];
    const int base = wave_in_block * 64;
    inv_r_s[base + ridx] = lane;
    inv_s_s[base + sidx] = lane;
    __syncthreads();
    const int inv_r = inv_r_s[base + lane];  // edge whose recv == my agent
    const int inv_s = inv_s_s[base + lane];  // edge whose send == my agent

    // ---- grid-stride, 4 rows per iteration = 2 packed f16x2 streams
    for (int row0 = gwave * ROWS; row0 < B; row0 += total_waves * ROWS) {
        float xv[ROWS], xs[ROWS], xr[ROWS];
#pragma unroll
        for (int k = 0; k < ROWS; ++k) {
            const int row = row0 + k;
            xv[k] = (row < B) ? x[(size_t)row * N_AGENTS + lane] : 0.0f;
        }
#pragma unroll
        for (int k = 0; k < ROWS; ++k) xr[k] = __shfl(xv[k], ridx, 64);
        if (send_is_id) {
#pragma unroll
            for (int k = 0; k < ROWS; ++k) xs[k] = xv[k];
        } else {
#pragma unroll
            for (int k = 0; k < ROWS; ++k) xs[k] = __shfl(xv[k], sidx, 64);
        }

        h2 C[2] = {c0h, c0h};   // coupling accumulators (2 rows per pack)
        h2 A[2] = {a0h, a0h};   // intrinsic accumulators

#pragma unroll
        for (int p = 0; p < 2; ++p) {
            const int r0 = 2 * p, r1 = 2 * p + 1;
#pragma unroll
            for (int h = 0; h < H_DIM; ++h) {
                // coupling: layer-1 in f32 (accuracy), pack -> f16 tanh core
                const float ca0 = __builtin_fmaf(xs[r0], wcs[h],
                                  __builtin_fmaf(xr[r0], wcr[h], bc1v[h]));
                const float ca1 = __builtin_fmaf(xs[r1], wcs[h],
                                  __builtin_fmaf(xr[r1], wcr[h], bc1v[h]));
                C[p] = __builtin_elementwise_fma(tanh_pk(pack2(ca0, ca1), TC),
                                                 wc2h[h], C[p]);
                // intrinsic
                const float ia0 = __builtin_fmaf(xv[r0], w1v[h], b1v[h]);
                const float ia1 = __builtin_fmaf(xv[r1], w1v[h], b1v[h]);
                A[p] = __builtin_elementwise_fma(tanh_pk(pack2(ia0, ia1), TC),
                                                 w2h[h], A[p]);
            }
        }

        // symmetric scatter: +contrib at receiver, -contrib at sender
#pragma unroll
        for (int p = 0; p < 2; ++p) {
            int cbits; __builtin_memcpy(&cbits, &C[p], 4);
            const int crb = __shfl(cbits, inv_r, 64);
            h2 Cr; __builtin_memcpy(&Cr, &crb, 4);
            h2 Cs;
            if (send_is_id) {
                Cs = C[p];
            } else {
                const int csb = __shfl(cbits, inv_s, 64);
                __builtin_memcpy(&Cs, &csb, 4);
            }
            const h2 res = A[p] + (Cr - Cs);
            const int rowa = row0 + 2 * p, rowb = rowa + 1;
            if (rowa < B) out[(size_t)rowa * N_AGENTS + lane] = (float)res.x;
            if (rowb < B) out[(size_t)rowb * N_AGENTS + lane] = (float)res.y;
        }
    }
}

extern "C" void kernel_launch(void* const* d_in, const int* in_sizes, int n_in,
                              void* d_out, int out_size, void* d_ws, size_t ws_size,
                              hipStream_t stream) {
    const float* x   = (const float*)d_in[0];
    const float* W1  = (const float*)d_in[1];
    const float* b1  = (const float*)d_in[2];
    const float* W2  = (const float*)d_in[3];
    const float* b2  = (const float*)d_in[4];
    const float* Wc1 = (const float*)d_in[5];
    const float* bc1 = (const float*)d_in[6];
    const float* Wc2 = (const float*)d_in[7];
    const float* bc2 = (const float*)d_in[8];
    const int* send_idx = (const int*)d_in[9];
    const int* recv_idx = (const int*)d_in[10];

    const int B = in_sizes[0] / N_AGENTS;   // 131072

    // 2048 blocks x 4 waves = 8192 waves (all resident); ROWS=4 -> 4 iters
    const int blocks = 2048;
    networked_ode_kernel<<<blocks, dim3(256), 0, stream>>>(
        x, W1, b1, W2, b2, Wc1, bc1, Wc2, bc2, send_idx, recv_idx,
        (float*)d_out, B);
}